// Round 1
// baseline (7283.859 us; speedup 1.0000x reference)
//
#include <hip/hip_runtime.h>

constexpr int NN  = 50000;   // nodes
constexpr int NE  = 800000;  // edges
constexpr int CIN = 128;     // input channels
constexpr int CH  = 256;     // hidden channels
constexpr int NG  = 512;     // graphs

// ---------------- degree / dinv ----------------
__global__ void deg_kernel(const int* __restrict__ dst, float* __restrict__ deg, int E) {
    int e = blockIdx.x * blockDim.x + threadIdx.x;
    if (e < E) atomicAdd(&deg[dst[e]], 1.0f);
}

// in-place: deg -> dinv = rsqrt(deg + 1)   (self-loop guarantees deg >= 1)
__global__ void dinv_kernel(float* __restrict__ d, int n) {
    int i = blockIdx.x * blockDim.x + threadIdx.x;
    if (i < n) d[i] = rsqrtf(d[i] + 1.0f);
}

// ---------------- edge aggregation (scatter-add with atomics) ----------------
// C channels; C/4 lanes per edge, float4 per lane.
template <int C>
__global__ void edge_agg_kernel(const float* __restrict__ h,
                                const int* __restrict__ src,
                                const int* __restrict__ dst,
                                const float* __restrict__ dinv,
                                float* __restrict__ out, int E) {
    constexpr int TPE = C / 4;
    long long t = (long long)blockIdx.x * blockDim.x + threadIdx.x;
    int e = (int)(t / TPE);
    int l = (int)(t % TPE);
    if (e >= E) return;
    int s = src[e], d = dst[e];
    float nrm = dinv[s] * dinv[d];
    const float4 v = *(const float4*)(h + (long long)s * C + 4 * l);
    float* o = out + (long long)d * C + 4 * l;
    atomicAdd(o + 0, nrm * v.x);
    atomicAdd(o + 1, nrm * v.y);
    atomicAdd(o + 2, nrm * v.z);
    atomicAdd(o + 3, nrm * v.w);
}

// ---------------- layer-0 self-loop add: out += dinv^2 * x (elementwise rows) ----
__global__ void sl_add_kernel(const float4* __restrict__ x, const float* __restrict__ dinv,
                              float4* __restrict__ out, int n4, int c4_per_row) {
    int i = blockIdx.x * blockDim.x + threadIdx.x;
    if (i >= n4) return;
    int node = i / c4_per_row;
    float w = dinv[node] * dinv[node];
    float4 v = x[i];
    float4 o = out[i];
    o.x += w * v.x; o.y += w * v.y; o.z += w * v.z; o.w += w * v.w;
    out[i] = o;
}

// ---------------- fp32 tiled GEMM: C[M,256] = A[M,K] @ W[K,256] ----------------
// BM=64, BN=64, BK=16; 256 threads, 4x4 microtile per thread.
__global__ __launch_bounds__(256) void gemm_kernel(const float* __restrict__ A,
                                                   const float* __restrict__ W,
                                                   float* __restrict__ C, int M, int K) {
    __shared__ float As[64][17];
    __shared__ float Ws[16][64];
    int tid = threadIdx.x;
    int tx = tid & 15, ty = tid >> 4;
    int row0 = blockIdx.x * 64;
    int col0 = blockIdx.y * 64;
    float acc[4][4] = {};
    for (int k0 = 0; k0 < K; k0 += 16) {
        {   // A tile 64x16, one float4 per thread
            int r = tid >> 2;
            int c = (tid & 3) * 4;
            int gr = row0 + r;
            float4 v = make_float4(0.f, 0.f, 0.f, 0.f);
            if (gr < M) v = *(const float4*)(A + (long long)gr * K + k0 + c);
            As[r][c + 0] = v.x; As[r][c + 1] = v.y; As[r][c + 2] = v.z; As[r][c + 3] = v.w;
        }
        {   // W tile 16x64
            int c = tid & 63;
            int r = tid >> 6;  // 0..3
            #pragma unroll
            for (int rr = 0; rr < 4; rr++)
                Ws[r + rr * 4][c] = W[(long long)(k0 + r + rr * 4) * 256 + col0 + c];
        }
        __syncthreads();
        #pragma unroll
        for (int k = 0; k < 16; k++) {
            float a[4], w[4];
            #pragma unroll
            for (int i = 0; i < 4; i++) a[i] = As[ty * 4 + i][k];
            #pragma unroll
            for (int j = 0; j < 4; j++) w[j] = Ws[k][tx * 4 + j];
            #pragma unroll
            for (int i = 0; i < 4; i++)
                #pragma unroll
                for (int j = 0; j < 4; j++) acc[i][j] += a[i] * w[j];
        }
        __syncthreads();
    }
    #pragma unroll
    for (int i = 0; i < 4; i++) {
        int gr = row0 + ty * 4 + i;
        if (gr < M) {
            float4 v = make_float4(acc[i][0], acc[i][1], acc[i][2], acc[i][3]);
            *(float4*)(C + (long long)gr * 256 + col0 + tx * 4) = v;
        }
    }
}

// ---------------- bias + relu in place (layer 0 post-GEMM) ----------------
__global__ void bias_relu_kernel(float4* __restrict__ h, const float4* __restrict__ b, int n4) {
    int i = blockIdx.x * blockDim.x + threadIdx.x;
    if (i >= n4) return;
    float4 v = h[i];
    float4 bb = b[i & 63];   // 64 float4 per 256-ch row
    v.x = fmaxf(v.x + bb.x, 0.f);
    v.y = fmaxf(v.y + bb.y, 0.f);
    v.z = fmaxf(v.z + bb.z, 0.f);
    v.w = fmaxf(v.w + bb.w, 0.f);
    h[i] = v;
}

// ---------------- epilogue layers 1: agg = relu(agg + dinv^2*h + b) ----------------
__global__ void epi_kernel(float4* __restrict__ agg, const float4* __restrict__ h,
                           const float4* __restrict__ b, const float* __restrict__ dinv, int n4) {
    int i = blockIdx.x * blockDim.x + threadIdx.x;
    if (i >= n4) return;
    int node = i >> 6;
    float w = dinv[node] * dinv[node];
    float4 a = agg[i], v = h[i], bb = b[i & 63];
    a.x = fmaxf(a.x + w * v.x + bb.x, 0.f);
    a.y = fmaxf(a.y + w * v.y + bb.y, 0.f);
    a.z = fmaxf(a.z + w * v.z + bb.z, 0.f);
    a.w = fmaxf(a.w + w * v.w + bb.w, 0.f);
    agg[i] = a;
}

// ---------------- final epilogue + global_add_pool ----------------
__global__ void epi_pool_kernel(const float4* __restrict__ agg, const float4* __restrict__ h,
                                const float4* __restrict__ b, const float* __restrict__ dinv,
                                const int* __restrict__ batch, float* __restrict__ out, int n4) {
    int i = blockIdx.x * blockDim.x + threadIdx.x;
    if (i >= n4) return;
    int node = i >> 6;
    int c4 = i & 63;
    float w = dinv[node] * dinv[node];
    float4 a = agg[i], v = h[i], bb = b[c4];
    float r0 = fmaxf(a.x + w * v.x + bb.x, 0.f);
    float r1 = fmaxf(a.y + w * v.y + bb.y, 0.f);
    float r2 = fmaxf(a.z + w * v.z + bb.z, 0.f);
    float r3 = fmaxf(a.w + w * v.w + bb.w, 0.f);
    float* o = out + (long long)batch[node] * 256 + c4 * 4;
    atomicAdd(o + 0, r0);
    atomicAdd(o + 1, r1);
    atomicAdd(o + 2, r2);
    atomicAdd(o + 3, r3);
}

extern "C" void kernel_launch(void* const* d_in, const int* in_sizes, int n_in,
                              void* d_out, int out_size, void* d_ws, size_t ws_size,
                              hipStream_t stream) {
    const float* x   = (const float*)d_in[0];
    const float* W0  = (const float*)d_in[1];
    const float* b0  = (const float*)d_in[2];
    const float* W1  = (const float*)d_in[3];
    const float* b1  = (const float*)d_in[4];
    const float* W2  = (const float*)d_in[5];
    const float* b2  = (const float*)d_in[6];
    const int*   ei  = (const int*)d_in[7];
    const int*   src = ei;
    const int*   dst = ei + NE;
    const int*   batch = (const int*)d_in[8];
    float* out = (float*)d_out;

    char* ws = (char*)d_ws;
    float* A    = (float*)ws;                               // [NN, CH]
    float* B    = (float*)(ws + (size_t)NN * CH * 4);       // [NN, CH]
    float* dinv = (float*)(ws + 2ull * NN * CH * 4);        // [NN] (deg in-place)

    const int n4    = NN * (CH / 4);    // 3.2M float4 (256-ch)
    const int n4in  = NN * (CIN / 4);   // 1.6M float4 (128-ch)

    // --- normalization ---
    hipMemsetAsync(dinv, 0, (size_t)NN * 4, stream);
    deg_kernel<<<(NE + 255) / 256, 256, 0, stream>>>(dst, dinv, NE);
    dinv_kernel<<<(NN + 255) / 256, 256, 0, stream>>>(dinv, NN);

    // --- layer 0: aggregate x (128 ch) first, then GEMM ---
    hipMemsetAsync(B, 0, (size_t)NN * CIN * 4, stream);
    edge_agg_kernel<CIN><<<(NE * (CIN / 4) + 255) / 256, 256, 0, stream>>>(x, src, dst, dinv, B, NE);
    sl_add_kernel<<<(n4in + 255) / 256, 256, 0, stream>>>((const float4*)x, dinv, (float4*)B, n4in, CIN / 4);
    gemm_kernel<<<dim3((NN + 63) / 64, 4), 256, 0, stream>>>(B, W0, A, NN, CIN);
    bias_relu_kernel<<<(n4 + 255) / 256, 256, 0, stream>>>((float4*)A, (const float4*)b0, n4);

    // --- layer 1: GEMM then aggregate ---
    gemm_kernel<<<dim3((NN + 63) / 64, 4), 256, 0, stream>>>(A, W1, B, NN, CH);
    hipMemsetAsync(A, 0, (size_t)NN * CH * 4, stream);
    edge_agg_kernel<CH><<<(NE * (CH / 4) + 255) / 256, 256, 0, stream>>>(B, src, dst, dinv, A, NE);
    epi_kernel<<<(n4 + 255) / 256, 256, 0, stream>>>((float4*)A, (const float4*)B, (const float4*)b1, dinv, n4);

    // --- layer 2: GEMM then aggregate, fused pool ---
    gemm_kernel<<<dim3((NN + 63) / 64, 4), 256, 0, stream>>>(A, W2, B, NN, CH);
    hipMemsetAsync(A, 0, (size_t)NN * CH * 4, stream);
    edge_agg_kernel<CH><<<(NE * (CH / 4) + 255) / 256, 256, 0, stream>>>(B, src, dst, dinv, A, NE);
    hipMemsetAsync(out, 0, (size_t)NG * CH * 4, stream);
    epi_pool_kernel<<<(n4 + 255) / 256, 256, 0, stream>>>((const float4*)A, (const float4*)B,
                                                          (const float4*)b2, dinv, batch, out, n4);
}

// Round 2
// 928.076 us; speedup vs baseline: 7.8483x; 7.8483x over previous
//
#include <hip/hip_runtime.h>

constexpr int NN  = 50000;   // nodes
constexpr int NE  = 800000;  // edges
constexpr int CIN = 128;     // input channels
constexpr int CH  = 256;     // hidden channels
constexpr int NG  = 512;     // graphs

// ================= CSR build =================
__global__ void count_kernel(const int* __restrict__ dst, int* __restrict__ cnt, int E) {
    int e = blockIdx.x * blockDim.x + threadIdx.x;
    if (e < E) atomicAdd(&cnt[dst[e]], 1);
}

// Single-block exclusive scan of cnt[0..n) -> rowptr[0..n], plus dinv = rsqrt(cnt+1).
__global__ __launch_bounds__(1024) void scan_kernel(const int* __restrict__ cnt,
                                                    int* __restrict__ rowptr,
                                                    float* __restrict__ dinv, int n) {
    __shared__ int buf[1024];
    __shared__ int carry;
    int tid = threadIdx.x;
    if (tid == 0) carry = 0;
    __syncthreads();
    for (int base = 0; base < n; base += 1024) {
        int i = base + tid;
        int v = (i < n) ? cnt[i] : 0;
        buf[tid] = v;
        __syncthreads();
        #pragma unroll
        for (int off = 1; off < 1024; off <<= 1) {
            int t = (tid >= off) ? buf[tid - off] : 0;
            __syncthreads();
            buf[tid] += t;
            __syncthreads();
        }
        if (i < n) {
            rowptr[i] = carry + buf[tid] - v;           // exclusive
            dinv[i]   = rsqrtf((float)v + 1.0f);        // +1 self loop
        }
        __syncthreads();
        if (tid == 0) carry += buf[1023];
        __syncthreads();
    }
    if (tid == 0) rowptr[n] = carry;
}

__global__ void scatter_kernel(const int* __restrict__ src, const int* __restrict__ dst,
                               const int* __restrict__ rowptr, int* __restrict__ cursor,
                               int* __restrict__ col, int E) {
    int e = blockIdx.x * blockDim.x + threadIdx.x;
    if (e >= E) return;
    int d = dst[e];
    int p = rowptr[d] + atomicAdd(&cursor[d], 1);
    col[p] = src[e];
}

// ================= per-node gather aggregation =================
// One 64-lane wave per node; V = C/64 floats per lane (float4 for C=256, float2 for C=128).
// MODE 0: out = dd*sum + dd^2*self                  (layer-0 pre-GEMM, C=128)
// MODE 1: out = relu(dd*sum + dd^2*self + bias)     (hidden layers)
// MODE 2: like MODE 1 but atomicAdd into pooled out[batch[d]] (no node store)
template <int C, int MODE>
__global__ __launch_bounds__(256) void node_agg_kernel(
    const float* __restrict__ h, const int* __restrict__ rowptr,
    const int* __restrict__ col, const float* __restrict__ dinv,
    const float* __restrict__ bias, const int* __restrict__ batch,
    float* __restrict__ out, int n) {
    constexpr int V = C / 64;
    int wave = threadIdx.x >> 6;
    int lane = threadIdx.x & 63;
    int d = blockIdx.x * 4 + wave;
    if (d >= n) return;

    int beg = rowptr[d], end = rowptr[d + 1];
    float acc[V] = {};
    int e = beg;
    // 2-way unroll for load ILP
    for (; e + 1 < end; e += 2) {
        int s0 = col[e], s1 = col[e + 1];
        float w0 = dinv[s0], w1 = dinv[s1];
        const float* p0 = h + (size_t)s0 * C + lane * V;
        const float* p1 = h + (size_t)s1 * C + lane * V;
        if constexpr (V == 4) {
            float4 a = *(const float4*)p0;
            float4 b = *(const float4*)p1;
            acc[0] += w0 * a.x + w1 * b.x;
            acc[1] += w0 * a.y + w1 * b.y;
            acc[2] += w0 * a.z + w1 * b.z;
            acc[3] += w0 * a.w + w1 * b.w;
        } else {
            float2 a = *(const float2*)p0;
            float2 b = *(const float2*)p1;
            acc[0] += w0 * a.x + w1 * b.x;
            acc[1] += w0 * a.y + w1 * b.y;
        }
    }
    if (e < end) {
        int s = col[e];
        float w = dinv[s];
        const float* p = h + (size_t)s * C + lane * V;
        if constexpr (V == 4) {
            float4 a = *(const float4*)p;
            acc[0] += w * a.x; acc[1] += w * a.y; acc[2] += w * a.z; acc[3] += w * a.w;
        } else {
            float2 a = *(const float2*)p;
            acc[0] += w * a.x; acc[1] += w * a.y;
        }
    }

    float dd = dinv[d];
    float self[V];
    {
        const float* ps = h + (size_t)d * C + lane * V;
        if constexpr (V == 4) {
            float4 s4 = *(const float4*)ps;
            self[0] = s4.x; self[1] = s4.y; self[2] = s4.z; self[3] = s4.w;
        } else {
            float2 s2 = *(const float2*)ps;
            self[0] = s2.x; self[1] = s2.y;
        }
    }

    float r[V];
    #pragma unroll
    for (int i = 0; i < V; i++) {
        float v = dd * acc[i] + dd * dd * self[i];
        if constexpr (MODE >= 1) v = fmaxf(v + bias[lane * V + i], 0.0f);
        r[i] = v;
    }

    if constexpr (MODE == 2) {
        float* o = out + (size_t)batch[d] * C + lane * V;
        #pragma unroll
        for (int i = 0; i < V; i++) atomicAdd(o + i, r[i]);
    } else {
        float* o = out + (size_t)d * C + lane * V;
        if constexpr (V == 4) {
            *(float4*)o = make_float4(r[0], r[1], r[2], r[3]);
        } else {
            *(float2*)o = make_float2(r[0], r[1]);
        }
    }
}

// ================= fp32 tiled GEMM: C[M,256] = A[M,K] @ W[K,256] =================
__global__ __launch_bounds__(256) void gemm_kernel(const float* __restrict__ A,
                                                   const float* __restrict__ W,
                                                   float* __restrict__ C, int M, int K) {
    __shared__ float As[64][17];
    __shared__ float Ws[16][64];
    int tid = threadIdx.x;
    int tx = tid & 15, ty = tid >> 4;
    int row0 = blockIdx.x * 64;
    int col0 = blockIdx.y * 64;
    float acc[4][4] = {};
    for (int k0 = 0; k0 < K; k0 += 16) {
        {
            int r = tid >> 2;
            int c = (tid & 3) * 4;
            int gr = row0 + r;
            float4 v = make_float4(0.f, 0.f, 0.f, 0.f);
            if (gr < M) v = *(const float4*)(A + (long long)gr * K + k0 + c);
            As[r][c + 0] = v.x; As[r][c + 1] = v.y; As[r][c + 2] = v.z; As[r][c + 3] = v.w;
        }
        {
            int c = tid & 63;
            int r = tid >> 6;
            #pragma unroll
            for (int rr = 0; rr < 4; rr++)
                Ws[r + rr * 4][c] = W[(long long)(k0 + r + rr * 4) * 256 + col0 + c];
        }
        __syncthreads();
        #pragma unroll
        for (int k = 0; k < 16; k++) {
            float a[4], w[4];
            #pragma unroll
            for (int i = 0; i < 4; i++) a[i] = As[ty * 4 + i][k];
            #pragma unroll
            for (int j = 0; j < 4; j++) w[j] = Ws[k][tx * 4 + j];
            #pragma unroll
            for (int i = 0; i < 4; i++)
                #pragma unroll
                for (int j = 0; j < 4; j++) acc[i][j] += a[i] * w[j];
        }
        __syncthreads();
    }
    #pragma unroll
    for (int i = 0; i < 4; i++) {
        int gr = row0 + ty * 4 + i;
        if (gr < M) {
            float4 v = make_float4(acc[i][0], acc[i][1], acc[i][2], acc[i][3]);
            *(float4*)(C + (long long)gr * 256 + col0 + tx * 4) = v;
        }
    }
}

// bias + relu in place (layer 0 post-GEMM)
__global__ void bias_relu_kernel(float4* __restrict__ h, const float4* __restrict__ b, int n4) {
    int i = blockIdx.x * blockDim.x + threadIdx.x;
    if (i >= n4) return;
    float4 v = h[i];
    float4 bb = b[i & 63];
    v.x = fmaxf(v.x + bb.x, 0.f);
    v.y = fmaxf(v.y + bb.y, 0.f);
    v.z = fmaxf(v.z + bb.z, 0.f);
    v.w = fmaxf(v.w + bb.w, 0.f);
    h[i] = v;
}

extern "C" void kernel_launch(void* const* d_in, const int* in_sizes, int n_in,
                              void* d_out, int out_size, void* d_ws, size_t ws_size,
                              hipStream_t stream) {
    const float* x   = (const float*)d_in[0];
    const float* W0  = (const float*)d_in[1];
    const float* b0  = (const float*)d_in[2];
    const float* W1  = (const float*)d_in[3];
    const float* b1  = (const float*)d_in[4];
    const float* W2  = (const float*)d_in[5];
    const float* b2  = (const float*)d_in[6];
    const int*   ei  = (const int*)d_in[7];
    const int*   src = ei;
    const int*   dst = ei + NE;
    const int*   batch = (const int*)d_in[8];
    float* out = (float*)d_out;

    char* ws = (char*)d_ws;
    float* A      = (float*)ws;                                  // [NN, 256] 51.2 MB
    float* B      = (float*)(ws + 51200000ull);                  // [NN, 256] 51.2 MB
    float* dinv   = (float*)(ws + 102400000ull);                 // [NN]
    int*   rowptr = (int*)  (ws + 102600000ull);                 // [NN+1]
    int*   cnt    = (int*)  (ws + 102800004ull);                 // [NN] counts, then cursor
    int*   col    = (int*)  (ws + 103000004ull);                 // [NE]

    const int n4 = NN * (CH / 4);
    const int nodeBlocks = (NN + 3) / 4;

    // --- CSR + normalization ---
    hipMemsetAsync(cnt, 0, (size_t)NN * 4, stream);
    count_kernel<<<(NE + 255) / 256, 256, 0, stream>>>(dst, cnt, NE);
    scan_kernel<<<1, 1024, 0, stream>>>(cnt, rowptr, dinv, NN);
    hipMemsetAsync(cnt, 0, (size_t)NN * 4, stream);              // reuse as cursor
    scatter_kernel<<<(NE + 255) / 256, 256, 0, stream>>>(src, dst, rowptr, cnt, col, NE);

    // --- layer 0: aggregate x (128 ch), then GEMM + bias + relu ---
    node_agg_kernel<CIN, 0><<<nodeBlocks, 256, 0, stream>>>(x, rowptr, col, dinv, nullptr, nullptr, B, NN);
    gemm_kernel<<<dim3((NN + 63) / 64, 4), 256, 0, stream>>>(B, W0, A, NN, CIN);
    bias_relu_kernel<<<(n4 + 255) / 256, 256, 0, stream>>>((float4*)A, (const float4*)b0, n4);

    // --- layer 1: GEMM then aggregate (fused bias+relu) ---
    gemm_kernel<<<dim3((NN + 63) / 64, 4), 256, 0, stream>>>(A, W1, B, NN, CH);
    node_agg_kernel<CH, 1><<<nodeBlocks, 256, 0, stream>>>(B, rowptr, col, dinv, b1, nullptr, A, NN);

    // --- layer 2: GEMM then aggregate (fused bias+relu+pool) ---
    gemm_kernel<<<dim3((NN + 63) / 64, 4), 256, 0, stream>>>(A, W2, B, NN, CH);
    hipMemsetAsync(out, 0, (size_t)NG * CH * 4, stream);
    node_agg_kernel<CH, 2><<<nodeBlocks, 256, 0, stream>>>(B, rowptr, col, dinv, b2, batch, out, NN);
}

// Round 3
// 587.649 us; speedup vs baseline: 12.3949x; 1.5793x over previous
//
#include <hip/hip_runtime.h>

constexpr int NN  = 50000;   // nodes
constexpr int NE  = 800000;  // edges
constexpr int CIN = 128;     // input channels
constexpr int CH  = 256;     // hidden channels
constexpr int NG  = 512;     // graphs

typedef unsigned short ushort_t;
typedef unsigned int uint_t;

static __device__ __forceinline__ float bf2f(ushort_t u) {
    return __uint_as_float(((uint_t)u) << 16);
}
static __device__ __forceinline__ ushort_t f2bf(float f) {
    uint_t u = __float_as_uint(f);
    u += 0x7fffu + ((u >> 16) & 1u);   // round-to-nearest-even
    return (ushort_t)(u >> 16);
}

// ================= prep: fp32 -> bf16 converts =================
__global__ void conv_x_kernel(const float4* __restrict__ x, ushort4* __restrict__ xb, int n4) {
    int i = blockIdx.x * blockDim.x + threadIdx.x;
    if (i >= n4) return;
    float4 v = x[i];
    ushort4 o;
    o.x = f2bf(v.x); o.y = f2bf(v.y); o.z = f2bf(v.z); o.w = f2bf(v.w);
    xb[i] = o;
}

// Wt[n*K + k] = bf16(W[k*N + n])
__global__ void conv_wt_kernel(const float* __restrict__ W, ushort_t* __restrict__ Wt, int K, int N) {
    int i = blockIdx.x * blockDim.x + threadIdx.x;
    if (i >= K * N) return;
    int k = i / N, n = i % N;
    Wt[(size_t)n * K + k] = f2bf(W[i]);
}

// ================= CSR build =================
__global__ void count_kernel(const int* __restrict__ dst, int* __restrict__ cnt, int E) {
    int e = blockIdx.x * blockDim.x + threadIdx.x;
    if (e < E) atomicAdd(&cnt[dst[e]], 1);
}

// single-block scan, shuffle-based (3 barriers per 1024-chunk)
__global__ __launch_bounds__(1024) void scan_kernel(const int* __restrict__ cnt,
                                                    int* __restrict__ rowptr,
                                                    float* __restrict__ dinv, int n) {
    __shared__ int wsum[16];
    __shared__ int carry_s;
    int tid = threadIdx.x, lane = tid & 63, wid = tid >> 6;
    if (tid == 0) carry_s = 0;
    __syncthreads();
    for (int base = 0; base < n; base += 1024) {
        int i = base + tid;
        int v = (i < n) ? cnt[i] : 0;
        int s = v;
        #pragma unroll
        for (int off = 1; off < 64; off <<= 1) {
            int t = __shfl_up(s, off, 64);
            if (lane >= off) s += t;
        }
        if (lane == 63) wsum[wid] = s;
        __syncthreads();
        if (wid == 0) {
            int ws = (lane < 16) ? wsum[lane] : 0;
            #pragma unroll
            for (int off = 1; off < 16; off <<= 1) {
                int t = __shfl_up(ws, off, 64);
                if (lane >= off) ws += t;
            }
            if (lane < 16) wsum[lane] = ws;
        }
        __syncthreads();
        int wave_excl = (wid == 0) ? 0 : wsum[wid - 1];
        int incl = carry_s + wave_excl + s;
        if (i < n) {
            rowptr[i] = incl - v;                 // exclusive
            dinv[i]   = rsqrtf((float)v + 1.0f);  // +1 self loop
        }
        __syncthreads();
        if (tid == 1023) carry_s = incl;
        __syncthreads();
    }
    if (tid == 0) rowptr[n] = carry_s;
}

__global__ void scatter_kernel(const int* __restrict__ src, const int* __restrict__ dst,
                               const int* __restrict__ rowptr, int* __restrict__ cursor,
                               int* __restrict__ col, int E) {
    int e = blockIdx.x * blockDim.x + threadIdx.x;
    if (e >= E) return;
    int d = dst[e];
    int p = rowptr[d] + atomicAdd(&cursor[d], 1);
    col[p] = src[e];
}

// ================= per-node gather aggregation (bf16 features) =================
// One wave per node; V = C/64 bf16 per lane.
// MODE 0: out(bf16) = dd*sum + dd^2*self                  (layer-0, C=128)
// MODE 1: out(bf16) = relu(dd*sum + dd^2*self + bias)     (hidden layer)
// MODE 2: atomicAdd relu(...) into fp32 out[batch[d]]     (final + pool)
template <int C, int MODE>
__global__ __launch_bounds__(256) void node_agg_kernel(
    const ushort_t* __restrict__ h, const int* __restrict__ rowptr,
    const int* __restrict__ col, const float* __restrict__ dinv,
    const float* __restrict__ bias, const int* __restrict__ batch,
    void* __restrict__ out_v, int n) {
    constexpr int V = C / 64;
    int wave = threadIdx.x >> 6;
    int lane = threadIdx.x & 63;
    int d = blockIdx.x * 4 + wave;
    if (d >= n) return;

    int beg = rowptr[d], end = rowptr[d + 1];
    float acc[V] = {};
    int e = beg;
    for (; e + 3 < end; e += 4) {
        int s0 = col[e], s1 = col[e + 1], s2 = col[e + 2], s3 = col[e + 3];
        float w0 = dinv[s0], w1 = dinv[s1], w2 = dinv[s2], w3 = dinv[s3];
        if constexpr (V == 4) {
            ushort4 a = *(const ushort4*)(h + (size_t)s0 * C + lane * 4);
            ushort4 b = *(const ushort4*)(h + (size_t)s1 * C + lane * 4);
            ushort4 c = *(const ushort4*)(h + (size_t)s2 * C + lane * 4);
            ushort4 dv = *(const ushort4*)(h + (size_t)s3 * C + lane * 4);
            acc[0] += w0 * bf2f(a.x) + w1 * bf2f(b.x) + w2 * bf2f(c.x) + w3 * bf2f(dv.x);
            acc[1] += w0 * bf2f(a.y) + w1 * bf2f(b.y) + w2 * bf2f(c.y) + w3 * bf2f(dv.y);
            acc[2] += w0 * bf2f(a.z) + w1 * bf2f(b.z) + w2 * bf2f(c.z) + w3 * bf2f(dv.z);
            acc[3] += w0 * bf2f(a.w) + w1 * bf2f(b.w) + w2 * bf2f(c.w) + w3 * bf2f(dv.w);
        } else {
            ushort2 a = *(const ushort2*)(h + (size_t)s0 * C + lane * 2);
            ushort2 b = *(const ushort2*)(h + (size_t)s1 * C + lane * 2);
            ushort2 c = *(const ushort2*)(h + (size_t)s2 * C + lane * 2);
            ushort2 dv = *(const ushort2*)(h + (size_t)s3 * C + lane * 2);
            acc[0] += w0 * bf2f(a.x) + w1 * bf2f(b.x) + w2 * bf2f(c.x) + w3 * bf2f(dv.x);
            acc[1] += w0 * bf2f(a.y) + w1 * bf2f(b.y) + w2 * bf2f(c.y) + w3 * bf2f(dv.y);
        }
    }
    for (; e < end; e++) {
        int s = col[e];
        float w = dinv[s];
        if constexpr (V == 4) {
            ushort4 a = *(const ushort4*)(h + (size_t)s * C + lane * 4);
            acc[0] += w * bf2f(a.x); acc[1] += w * bf2f(a.y);
            acc[2] += w * bf2f(a.z); acc[3] += w * bf2f(a.w);
        } else {
            ushort2 a = *(const ushort2*)(h + (size_t)s * C + lane * 2);
            acc[0] += w * bf2f(a.x); acc[1] += w * bf2f(a.y);
        }
    }

    float dd = dinv[d];
    float self[V];
    if constexpr (V == 4) {
        ushort4 s4 = *(const ushort4*)(h + (size_t)d * C + lane * 4);
        self[0] = bf2f(s4.x); self[1] = bf2f(s4.y); self[2] = bf2f(s4.z); self[3] = bf2f(s4.w);
    } else {
        ushort2 s2 = *(const ushort2*)(h + (size_t)d * C + lane * 2);
        self[0] = bf2f(s2.x); self[1] = bf2f(s2.y);
    }

    float r[V];
    #pragma unroll
    for (int i = 0; i < V; i++) {
        float v = dd * acc[i] + dd * dd * self[i];
        if constexpr (MODE >= 1) v = fmaxf(v + bias[lane * V + i], 0.0f);
        r[i] = v;
    }

    if constexpr (MODE == 2) {
        float* o = (float*)out_v + (size_t)batch[d] * C + lane * V;
        #pragma unroll
        for (int i = 0; i < V; i++) atomicAdd(o + i, r[i]);
    } else if constexpr (V == 4) {
        ushort4 o;
        o.x = f2bf(r[0]); o.y = f2bf(r[1]); o.z = f2bf(r[2]); o.w = f2bf(r[3]);
        *(ushort4*)((ushort_t*)out_v + (size_t)d * C + lane * 4) = o;
    } else {
        ushort2 o;
        o.x = f2bf(r[0]); o.y = f2bf(r[1]);
        *(ushort2*)((ushort_t*)out_v + (size_t)d * C + lane * 2) = o;
    }
}

// ================= bf16 MFMA GEMM: C[M,256] = A[M,K] @ Wt[N,K]^T =================
// BM=128, BN=128, BK=32; 256 threads = 4 waves (2x2), each wave 64x64 via 4x4 mfma_16x16x32.
// MODE 0: plain bf16 store.  MODE 1: bias+relu then bf16 store.
typedef __attribute__((ext_vector_type(8))) short bf16x8;
typedef __attribute__((ext_vector_type(4))) float f32x4;

template <int MODE>
__global__ __launch_bounds__(256) void gemm_bf16_kernel(
    const ushort_t* __restrict__ A, const ushort_t* __restrict__ Wt,
    const float* __restrict__ bias, ushort_t* __restrict__ C, int M, int K) {
    __shared__ ushort_t As[128][40];   // 32 used + 8 pad (keeps 16B align)
    __shared__ ushort_t Bs[128][40];
    int tid = threadIdx.x;
    int row0 = blockIdx.x * 128, col0 = blockIdx.y * 128;
    int lr = tid >> 2, lq = tid & 3;          // load: rows lr, lr+64; 16B chunk lq
    int lane = tid & 63, wv = tid >> 6;
    int wr = (wv >> 1) * 64, wc = (wv & 1) * 64;
    int r16 = lane & 15, quad = lane >> 4;

    f32x4 acc[4][4] = {};

    for (int k0 = 0; k0 < K; k0 += 32) {
        {
            int gr0 = row0 + lr, gr1 = row0 + lr + 64;
            uint4 a0 = make_uint4(0, 0, 0, 0), a1 = make_uint4(0, 0, 0, 0);
            if (gr0 < M) a0 = *(const uint4*)(A + (size_t)gr0 * K + k0 + lq * 8);
            if (gr1 < M) a1 = *(const uint4*)(A + (size_t)gr1 * K + k0 + lq * 8);
            *(uint4*)&As[lr][lq * 8]      = a0;
            *(uint4*)&As[lr + 64][lq * 8] = a1;
            uint4 b0 = *(const uint4*)(Wt + (size_t)(col0 + lr) * K + k0 + lq * 8);
            uint4 b1 = *(const uint4*)(Wt + (size_t)(col0 + lr + 64) * K + k0 + lq * 8);
            *(uint4*)&Bs[lr][lq * 8]      = b0;
            *(uint4*)&Bs[lr + 64][lq * 8] = b1;
        }
        __syncthreads();
        bf16x8 af[4], bfr[4];
        #pragma unroll
        for (int i = 0; i < 4; i++) af[i]  = *(const bf16x8*)&As[wr + i * 16 + r16][quad * 8];
        #pragma unroll
        for (int j = 0; j < 4; j++) bfr[j] = *(const bf16x8*)&Bs[wc + j * 16 + r16][quad * 8];
        #pragma unroll
        for (int i = 0; i < 4; i++)
            #pragma unroll
            for (int j = 0; j < 4; j++)
                acc[i][j] = __builtin_amdgcn_mfma_f32_16x16x32_bf16(af[i], bfr[j], acc[i][j], 0, 0, 0);
        __syncthreads();
    }

    #pragma unroll
    for (int j = 0; j < 4; j++) {
        int colc = col0 + wc + j * 16 + r16;
        float bval = (MODE == 1) ? bias[colc] : 0.0f;
        #pragma unroll
        for (int i = 0; i < 4; i++) {
            #pragma unroll
            for (int r = 0; r < 4; r++) {
                int row = row0 + wr + i * 16 + quad * 4 + r;
                if (row < M) {
                    float v = acc[i][j][r];
                    if (MODE == 1) v = fmaxf(v + bval, 0.0f);
                    C[(size_t)row * 256 + colc] = f2bf(v);
                }
            }
        }
    }
}

extern "C" void kernel_launch(void* const* d_in, const int* in_sizes, int n_in,
                              void* d_out, int out_size, void* d_ws, size_t ws_size,
                              hipStream_t stream) {
    const float* x   = (const float*)d_in[0];
    const float* W0  = (const float*)d_in[1];
    const float* b0  = (const float*)d_in[2];
    const float* W1  = (const float*)d_in[3];
    const float* b1  = (const float*)d_in[4];
    const float* W2  = (const float*)d_in[5];
    const float* b2  = (const float*)d_in[6];
    const int*   ei  = (const int*)d_in[7];
    const int*   src = ei;
    const int*   dst = ei + NE;
    const int*   batch = (const int*)d_in[8];
    float* out = (float*)d_out;

    char* ws = (char*)d_ws;
    ushort_t* Abf = (ushort_t*)ws;                        // [NN,256] bf16  25.6 MB
    ushort_t* Bbf = (ushort_t*)(ws + 25600000ull);        // [NN,256] bf16  25.6 MB (also holds [NN,128])
    ushort_t* xbf = (ushort_t*)(ws + 51200000ull);        // [NN,128] bf16  12.8 MB
    ushort_t* W0t = (ushort_t*)(ws + 64000000ull);        // [256,128] bf16
    ushort_t* W1t = (ushort_t*)(ws + 64065536ull);        // [256,256] bf16
    ushort_t* W2t = (ushort_t*)(ws + 64196608ull);        // [256,256] bf16
    float*    dinv   = (float*)(ws + 64327680ull);        // [NN]
    int*      rowptr = (int*)  (ws + 64527680ull);        // [NN+1]
    int*      cnt    = (int*)  (ws + 64727808ull);        // [NN]
    int*      col    = (int*)  (ws + 64927808ull);        // [NE]

    const int nodeBlocks = (NN + 3) / 4;
    const dim3 ggrid((NN + 127) / 128, 2);

    // --- prep converts ---
    conv_x_kernel<<<(NN * CIN / 4 + 255) / 256, 256, 0, stream>>>((const float4*)x, (ushort4*)xbf, NN * CIN / 4);
    conv_wt_kernel<<<(CIN * CH + 255) / 256, 256, 0, stream>>>(W0, W0t, CIN, CH);
    conv_wt_kernel<<<(CH * CH + 255) / 256, 256, 0, stream>>>(W1, W1t, CH, CH);
    conv_wt_kernel<<<(CH * CH + 255) / 256, 256, 0, stream>>>(W2, W2t, CH, CH);

    // --- CSR + normalization ---
    hipMemsetAsync(cnt, 0, (size_t)NN * 4, stream);
    count_kernel<<<(NE + 255) / 256, 256, 0, stream>>>(dst, cnt, NE);
    scan_kernel<<<1, 1024, 0, stream>>>(cnt, rowptr, dinv, NN);
    hipMemsetAsync(cnt, 0, (size_t)NN * 4, stream);       // reuse as cursor
    scatter_kernel<<<(NE + 255) / 256, 256, 0, stream>>>(src, dst, rowptr, cnt, col, NE);

    // --- layer 0: aggregate x (128 ch, bf16), GEMM0 fused bias+relu ---
    node_agg_kernel<CIN, 0><<<nodeBlocks, 256, 0, stream>>>(xbf, rowptr, col, dinv, nullptr, nullptr, Bbf, NN);
    gemm_bf16_kernel<1><<<ggrid, 256, 0, stream>>>(Bbf, W0t, b0, Abf, NN, CIN);

    // --- layer 1: GEMM1 plain, aggregate fused bias+relu ---
    gemm_bf16_kernel<0><<<ggrid, 256, 0, stream>>>(Abf, W1t, nullptr, Bbf, NN, CH);
    node_agg_kernel<CH, 1><<<nodeBlocks, 256, 0, stream>>>(Bbf, rowptr, col, dinv, b1, nullptr, Abf, NN);

    // --- layer 2: GEMM2 plain, aggregate fused bias+relu+pool ---
    gemm_bf16_kernel<0><<<ggrid, 256, 0, stream>>>(Abf, W2t, nullptr, Bbf, NN, CH);
    hipMemsetAsync(out, 0, (size_t)NG * CH * 4, stream);
    node_agg_kernel<CH, 2><<<nodeBlocks, 256, 0, stream>>>(Bbf, rowptr, col, dinv, b2, batch, out, NN);
}